// Round 6
// baseline (180.282 us; speedup 1.0000x reference)
//
#include <hip/hip_runtime.h>

#define N_NODES 100000
#define N_EDGES 1600000
#define IN_F 256
#define OUT_F 128

#define NB 512               // buckets (bucket = row / RPB); bucket 511 empty
#define RPB 196              // rows per bucket
#define NBUSED ((N_NODES + RPB - 1) / RPB)        // 511
#define TILE 8192
#define NTILES ((N_EDGES + TILE - 1) / TILE)      // 196

typedef unsigned long long ull;
typedef __attribute__((ext_vector_type(4))) float f32x4;
typedef __attribute__((ext_vector_type(8))) short bf16x8;

__device__ __forceinline__ unsigned short f2bf(float f) {
    unsigned u = __float_as_uint(f);
    unsigned r = u + 0x7FFF + ((u >> 16) & 1);    // round-to-nearest-even
    return (unsigned short)(r >> 16);
}
__device__ __forceinline__ float bflo(unsigned u) { return __uint_as_float(u << 16); }
__device__ __forceinline__ float bfhi(unsigned u) { return __uint_as_float(u & 0xFFFF0000u); }

// ---------------------------------------------------------------------------
// W convert: Wt[n][k] = bf16(W[k][n])
// ---------------------------------------------------------------------------
__global__ __launch_bounds__(256) void wconv_kernel(const float* __restrict__ W,
                                                    unsigned short* __restrict__ Wt) {
    int idx = blockIdx.x * 256 + threadIdx.x;      // 32768 total
    int n = idx >> 8;
    int k = idx & 255;
    Wt[n * IN_F + k] = f2bf(W[k * OUT_F + n]);
}

// ---------------------------------------------------------------------------
// MFMA GEMM: support_bf[100000,128](bf16) = X[100000,256] @ W
// 128x128 tile, BK=32, 4 waves (2x2), 64x64 per wave.
// Software-pipelined: next k-step's global loads issued before the barrier,
// so HBM latency hides under MFMA (T14-lite).
// ---------------------------------------------------------------------------
__global__ __launch_bounds__(256) void gemm_mfma_kernel(const float* __restrict__ X,
                                                        const unsigned short* __restrict__ Wt,
                                                        unsigned short* __restrict__ support_bf) {
    __shared__ __align__(16) unsigned short Albs[4][128][8];   // 8 KB
    __shared__ __align__(16) unsigned short Blbs[4][128][8];   // 8 KB

    const int tid = threadIdx.x;
    const int block_row = blockIdx.x * 128;

    const int srow = tid >> 1;          // 0..127
    const int shalf = tid & 1;

    const int wid = tid >> 6;
    const int lane = tid & 63;
    const int wr = wid >> 1, wc = wid & 1;
    const int fr = lane & 15;
    const int kb = lane >> 4;

    const int agrow = block_row + srow;
    const bool arow_ok = (agrow < N_NODES);
    const float* xrow = X + (long)agrow * IN_F;
    const unsigned short* wrow = Wt + srow * IN_F;

    f32x4 acc[4][4];
#pragma unroll
    for (int m = 0; m < 4; ++m)
#pragma unroll
        for (int n = 0; n < 4; ++n) acc[m][n] = (f32x4)0.f;

    // prologue loads (k0 = 0)
    float4 c0, c1, c2, c3;
    bf16x8 cb0, cb1;
    if (arow_ok) {
        c0 = *(const float4*)&xrow[shalf * 16 + 0];
        c1 = *(const float4*)&xrow[shalf * 16 + 4];
        c2 = *(const float4*)&xrow[shalf * 16 + 8];
        c3 = *(const float4*)&xrow[shalf * 16 + 12];
    } else {
        c0 = c1 = c2 = c3 = make_float4(0.f, 0.f, 0.f, 0.f);
    }
    cb0 = *(const bf16x8*)&wrow[shalf * 16];
    cb1 = *(const bf16x8*)&wrow[shalf * 16 + 8];

#pragma unroll
    for (int k0 = 0; k0 < IN_F; k0 += 32) {
        // ---- stage current into LDS ----
        {
            bf16x8 p0, p1;
            p0[0] = (short)f2bf(c0.x); p0[1] = (short)f2bf(c0.y);
            p0[2] = (short)f2bf(c0.z); p0[3] = (short)f2bf(c0.w);
            p0[4] = (short)f2bf(c1.x); p0[5] = (short)f2bf(c1.y);
            p0[6] = (short)f2bf(c1.z); p0[7] = (short)f2bf(c1.w);
            p1[0] = (short)f2bf(c2.x); p1[1] = (short)f2bf(c2.y);
            p1[2] = (short)f2bf(c2.z); p1[3] = (short)f2bf(c2.w);
            p1[4] = (short)f2bf(c3.x); p1[5] = (short)f2bf(c3.y);
            p1[6] = (short)f2bf(c3.z); p1[7] = (short)f2bf(c3.w);
            *(bf16x8*)&Albs[shalf * 2][srow][0]     = p0;
            *(bf16x8*)&Albs[shalf * 2 + 1][srow][0] = p1;
            *(bf16x8*)&Blbs[shalf * 2][srow][0]     = cb0;
            *(bf16x8*)&Blbs[shalf * 2 + 1][srow][0] = cb1;
        }
        // ---- prefetch next k-step (overlaps barrier + MFMA) ----
        float4 n0, n1, n2, n3;
        bf16x8 nb0, nb1;
        if (k0 + 32 < IN_F) {
            int kn = k0 + 32;
            if (arow_ok) {
                n0 = *(const float4*)&xrow[kn + shalf * 16 + 0];
                n1 = *(const float4*)&xrow[kn + shalf * 16 + 4];
                n2 = *(const float4*)&xrow[kn + shalf * 16 + 8];
                n3 = *(const float4*)&xrow[kn + shalf * 16 + 12];
            } else {
                n0 = n1 = n2 = n3 = make_float4(0.f, 0.f, 0.f, 0.f);
            }
            nb0 = *(const bf16x8*)&wrow[kn + shalf * 16];
            nb1 = *(const bf16x8*)&wrow[kn + shalf * 16 + 8];
        }
        __syncthreads();

        // ---- compute ----
        bf16x8 af[4], bfr[4];
#pragma unroll
        for (int m = 0; m < 4; ++m)
            af[m] = *(const bf16x8*)&Albs[kb][wr * 64 + m * 16 + fr][0];
#pragma unroll
        for (int n = 0; n < 4; ++n)
            bfr[n] = *(const bf16x8*)&Blbs[kb][wc * 64 + n * 16 + fr][0];
#pragma unroll
        for (int m = 0; m < 4; ++m)
#pragma unroll
            for (int n = 0; n < 4; ++n)
                acc[m][n] = __builtin_amdgcn_mfma_f32_16x16x32_bf16(af[m], bfr[n],
                                                                    acc[m][n], 0, 0, 0);
        __syncthreads();

        c0 = n0; c1 = n1; c2 = n2; c3 = n3;
        cb0 = nb0; cb1 = nb1;
    }

    // epilogue: C/D layout col=lane&15, row=(lane>>4)*4+reg ; write bf16
    const int crow0 = (lane >> 4) * 4;
    const int ccol = lane & 15;
#pragma unroll
    for (int m = 0; m < 4; ++m) {
#pragma unroll
        for (int reg = 0; reg < 4; ++reg) {
            int grow = block_row + wr * 64 + m * 16 + crow0 + reg;
            if (grow < N_NODES) {
#pragma unroll
                for (int n = 0; n < 4; ++n) {
                    int gcol = wc * 64 + n * 16 + ccol;
                    support_bf[(long)grow * OUT_F + gcol] = f2bf(acc[m][n][reg]);
                }
            }
        }
    }
}

// ---------------------------------------------------------------------------
// Bucket histogram (LDS-aggregated)
// ---------------------------------------------------------------------------
__global__ __launch_bounds__(1024) void bhist_kernel(const int* __restrict__ erow,
                                                     int* __restrict__ bucket_hist) {
    __shared__ int lh[NB];
    for (int i = threadIdx.x; i < NB; i += 1024) lh[i] = 0;
    __syncthreads();
    int e0 = blockIdx.x * TILE;
    int e1 = min(e0 + TILE, N_EDGES);
    for (int e = e0 + threadIdx.x; e < e1; e += 1024)
        atomicAdd(&lh[erow[e] / RPB], 1);
    __syncthreads();
    for (int i = threadIdx.x; i < NB; i += 1024)
        if (lh[i]) atomicAdd(&bucket_hist[i], lh[i]);
}

// ---------------------------------------------------------------------------
// Bucket scan (single block of 512)
// ---------------------------------------------------------------------------
__global__ __launch_bounds__(512) void bscan_kernel(const int* __restrict__ bucket_hist,
                                                    int* __restrict__ bucket_base,
                                                    int* __restrict__ bucket_cursor,
                                                    int* __restrict__ offsets) {
    __shared__ int p[512];
    const int tid = threadIdx.x;
    int v = bucket_hist[tid];
    p[tid] = v;
    __syncthreads();
#pragma unroll
    for (int off = 1; off < 512; off <<= 1) {
        int t = (tid >= off) ? p[tid - off] : 0;
        __syncthreads();
        p[tid] += t;
        __syncthreads();
    }
    bucket_base[tid] = p[tid] - v;
    bucket_cursor[tid] = p[tid] - v;
    if (tid == 511) bucket_base[512] = p[511];
    if (tid == 0) offsets[N_NODES] = N_EDGES;
}

// ---------------------------------------------------------------------------
// Pass 1: shuffle edges into bucket segments
// record = [val:f32 (63:32) | localrow:8 (31:24) | col:24 (23:0)]
// ---------------------------------------------------------------------------
__global__ __launch_bounds__(1024) void shuffle_kernel(const int* __restrict__ erow,
                                                       const int* __restrict__ ecol,
                                                       const float* __restrict__ eval,
                                                       int* __restrict__ bucket_cursor,
                                                       ull* __restrict__ bucketed) {
    __shared__ int lhist[NB];
    __shared__ int lbase[NB];
    const int e0 = blockIdx.x * TILE;
    const int e1 = min(e0 + TILE, N_EDGES);

    for (int i = threadIdx.x; i < NB; i += 1024) lhist[i] = 0;
    __syncthreads();
    for (int e = e0 + threadIdx.x; e < e1; e += 1024)
        atomicAdd(&lhist[erow[e] / RPB], 1);
    __syncthreads();
    for (int i = threadIdx.x; i < NB; i += 1024) {
        int c = lhist[i];
        lbase[i] = c ? atomicAdd(&bucket_cursor[i], c) : 0;
        lhist[i] = 0;                      // reuse as local cursor
    }
    __syncthreads();
    for (int e = e0 + threadIdx.x; e < e1; e += 1024) {
        int row = erow[e];                 // L2-hot re-read
        int b = row / RPB;
        int lr = row - b * RPB;
        int pos = lbase[b] + atomicAdd(&lhist[b], 1);
        ull rec = ((ull)__float_as_uint(eval[e]) << 32) |
                  ((unsigned)lr << 24) | (unsigned)ecol[e];
        bucketed[pos] = rec;
    }
}

// ---------------------------------------------------------------------------
// Pass 2: per-bucket counting sort by local row; emits offsets + sorted recs.
// ---------------------------------------------------------------------------
__global__ __launch_bounds__(256) void bsort_kernel(const int* __restrict__ bucket_base,
                                                    const ull* __restrict__ bucketed,
                                                    ull* __restrict__ sorted,
                                                    int* __restrict__ offsets) {
    const int b = blockIdx.x;
    const int r0 = b * RPB;
    if (r0 >= N_NODES) return;
    const int nrows = min(RPB, N_NODES - r0);
    const int start = bucket_base[b];
    const int cnt = bucket_base[b + 1] - start;

    __shared__ int lhist[RPB];
    __shared__ int lcur[RPB];
    __shared__ int lscan[256];
    const int tid = threadIdx.x;

    if (tid < RPB) lhist[tid] = 0;
    __syncthreads();
    for (int i = start + tid; i < start + cnt; i += 256) {
        int lr = (int)((bucketed[i] >> 24) & 0xFF);
        atomicAdd(&lhist[lr], 1);
    }
    __syncthreads();
    int v = (tid < RPB) ? lhist[tid] : 0;
    lscan[tid] = v;
    __syncthreads();
#pragma unroll
    for (int off = 1; off < 256; off <<= 1) {
        int t = (tid >= off) ? lscan[tid - off] : 0;
        __syncthreads();
        lscan[tid] += t;
        __syncthreads();
    }
    int excl = lscan[tid] - v;
    if (tid < nrows) {
        offsets[r0 + tid] = start + excl;
        lcur[tid] = excl;
    }
    __syncthreads();
    for (int i = start + tid; i < start + cnt; i += 256) {
        ull rec = bucketed[i];             // L2-hot second read
        int lr = (int)((rec >> 24) & 0xFF);
        int p = atomicAdd(&lcur[lr], 1);
        sorted[start + p] = rec;
    }
}

// ---------------------------------------------------------------------------
// SpMM: one wave per row; bf16 support gather; unroll-4 for MLP; NT streams.
// ---------------------------------------------------------------------------
__global__ __launch_bounds__(256) void spmm_kernel(const int* __restrict__ offsets,
                                                   const ull* __restrict__ sorted,
                                                   const unsigned short* __restrict__ sbf,
                                                   const float* __restrict__ b,
                                                   float* __restrict__ out) {
    const int wave = blockIdx.x * 4 + (threadIdx.x >> 6);
    const int lane = threadIdx.x & 63;
    if (wave >= N_NODES) return;

    const int row = wave;
    const int start = offsets[row];
    const int end = offsets[row + 1];

    float2 acc = *(const float2*)&b[lane * 2];
    const int lo = lane * 2;

    int e = start;
    const int n4 = start + ((end - start) & ~3);
    for (; e < n4; e += 4) {
        ull r0 = __builtin_nontemporal_load(&sorted[e]);
        ull r1 = __builtin_nontemporal_load(&sorted[e + 1]);
        ull r2 = __builtin_nontemporal_load(&sorted[e + 2]);
        ull r3 = __builtin_nontemporal_load(&sorted[e + 3]);
        float v0 = __uint_as_float((unsigned)(r0 >> 32));
        float v1 = __uint_as_float((unsigned)(r1 >> 32));
        float v2 = __uint_as_float((unsigned)(r2 >> 32));
        float v3 = __uint_as_float((unsigned)(r3 >> 32));
        unsigned u0 = *(const unsigned*)&sbf[(long)(r0 & 0xFFFFFF) * OUT_F + lo];
        unsigned u1 = *(const unsigned*)&sbf[(long)(r1 & 0xFFFFFF) * OUT_F + lo];
        unsigned u2 = *(const unsigned*)&sbf[(long)(r2 & 0xFFFFFF) * OUT_F + lo];
        unsigned u3 = *(const unsigned*)&sbf[(long)(r3 & 0xFFFFFF) * OUT_F + lo];
        acc.x += v0 * bflo(u0) + v1 * bflo(u1) + v2 * bflo(u2) + v3 * bflo(u3);
        acc.y += v0 * bfhi(u0) + v1 * bfhi(u1) + v2 * bfhi(u2) + v3 * bfhi(u3);
    }
    for (; e < end; ++e) {
        ull r0 = __builtin_nontemporal_load(&sorted[e]);
        float v0 = __uint_as_float((unsigned)(r0 >> 32));
        unsigned u0 = *(const unsigned*)&sbf[(long)(r0 & 0xFFFFFF) * OUT_F + lo];
        acc.x += v0 * bflo(u0);
        acc.y += v0 * bfhi(u0);
    }

    // streaming store (keep L2 for the gather table)
    __builtin_nontemporal_store(*(double*)&acc, (double*)&out[row * OUT_F + lo]);
}

extern "C" void kernel_launch(void* const* d_in, const int* in_sizes, int n_in,
                              void* d_out, int out_size, void* d_ws, size_t ws_size,
                              hipStream_t stream) {
    const float* x        = (const float*)d_in[0];
    const int*   edge_row = (const int*)d_in[1];
    const int*   edge_col = (const int*)d_in[2];
    const float* edge_val = (const float*)d_in[3];
    const float* weight   = (const float*)d_in[4];
    const float* bias     = (const float*)d_in[5];
    float* out = (float*)d_out;

    // workspace layout
    unsigned short* support_bf = (unsigned short*)d_ws;        // 12,800,000 u16 = 25.6 MB
    int* base_i        = (int*)d_ws + 6400000;
    int* bucket_hist   = base_i;                               // 512
    int* bucket_base   = base_i + 512;                         // 513
    int* bucket_cursor = base_i + 1032;                        // 512
    int* offsets       = base_i + 1544;                        // 100,001
    ull* bucketed = (ull*)(base_i + 101546);                   // 1,600,000 u64
    ull* sorted   = bucketed + N_EDGES;                        // 1,600,000 u64
    unsigned short* wt = (unsigned short*)(sorted + N_EDGES);  // 32,768 u16
    // total ≈ 52 MB

    // 0) W -> transposed bf16
    wconv_kernel<<<dim3(128), 256, 0, stream>>>(weight, wt);

    // 1) support_bf = bf16(X @ W)
    gemm_mfma_kernel<<<dim3((N_NODES + 127) / 128), 256, 0, stream>>>(x, wt, support_bf);

    // 2) bucket histogram
    hipMemsetAsync(bucket_hist, 0, NB * sizeof(int), stream);
    bhist_kernel<<<dim3(NTILES), 1024, 0, stream>>>(edge_row, bucket_hist);

    // 3) bucket scan -> base/cursor; offsets[N] = E
    bscan_kernel<<<dim3(1), 512, 0, stream>>>(bucket_hist, bucket_base, bucket_cursor, offsets);

    // 4) pass 1: shuffle into bucket segments
    shuffle_kernel<<<dim3(NTILES), 1024, 0, stream>>>(edge_row, edge_col, edge_val,
                                                      bucket_cursor, bucketed);

    // 5) pass 2: per-bucket counting sort -> sorted + offsets
    bsort_kernel<<<dim3(NBUSED), 256, 0, stream>>>(bucket_base, bucketed, sorted, offsets);

    // 6) SpMM
    spmm_kernel<<<dim3((N_NODES + 3) / 4), 256, 0, stream>>>(offsets, sorted, support_bf,
                                                             bias, out);
}

// Round 7
// 156.875 us; speedup vs baseline: 1.1492x; 1.1492x over previous
//
#include <hip/hip_runtime.h>

#define N_NODES 100000
#define N_EDGES 1600000
#define IN_F 256
#define OUT_F 128

#define NB 512               // buckets (bucket = row / RPB); bucket 511 empty
#define RPB 196              // rows per bucket
#define NBUSED ((N_NODES + RPB - 1) / RPB)        // 511
#define TILE 8192
#define NTILES ((N_EDGES + TILE - 1) / TILE)      // 196

typedef unsigned long long ull;
typedef __attribute__((ext_vector_type(4))) float f32x4;
typedef __attribute__((ext_vector_type(8))) short bf16x8;

__device__ __forceinline__ unsigned short f2bf(float f) {
    unsigned u = __float_as_uint(f);
    unsigned r = u + 0x7FFF + ((u >> 16) & 1);    // round-to-nearest-even
    return (unsigned short)(r >> 16);
}
__device__ __forceinline__ float bflo(unsigned u) { return __uint_as_float(u << 16); }
__device__ __forceinline__ float bfhi(unsigned u) { return __uint_as_float(u & 0xFFFF0000u); }

// ---------------------------------------------------------------------------
// W convert: Wt[n][k] = bf16(W[k][n])
// ---------------------------------------------------------------------------
__global__ __launch_bounds__(256) void wconv_kernel(const float* __restrict__ W,
                                                    unsigned short* __restrict__ Wt) {
    int idx = blockIdx.x * 256 + threadIdx.x;      // 32768 total
    int n = idx >> 8;
    int k = idx & 255;
    Wt[n * IN_F + k] = f2bf(W[k * OUT_F + n]);
}

// ---------------------------------------------------------------------------
// MFMA GEMM: support_bf[100000,128](bf16) = X[100000,256] @ W
// 128x128 tile, BK=32, 4 waves (2x2), 64x64 per wave. Reg-prefetch pipeline.
// ---------------------------------------------------------------------------
__global__ __launch_bounds__(256) void gemm_mfma_kernel(const float* __restrict__ X,
                                                        const unsigned short* __restrict__ Wt,
                                                        unsigned short* __restrict__ support_bf) {
    __shared__ __align__(16) unsigned short Albs[4][128][8];   // 8 KB
    __shared__ __align__(16) unsigned short Blbs[4][128][8];   // 8 KB

    const int tid = threadIdx.x;
    const int block_row = blockIdx.x * 128;

    const int srow = tid >> 1;          // 0..127
    const int shalf = tid & 1;

    const int wid = tid >> 6;
    const int lane = tid & 63;
    const int wr = wid >> 1, wc = wid & 1;
    const int fr = lane & 15;
    const int kb = lane >> 4;

    const int agrow = block_row + srow;
    const bool arow_ok = (agrow < N_NODES);
    const float* xrow = X + (long)agrow * IN_F;
    const unsigned short* wrow = Wt + srow * IN_F;

    f32x4 acc[4][4];
#pragma unroll
    for (int m = 0; m < 4; ++m)
#pragma unroll
        for (int n = 0; n < 4; ++n) acc[m][n] = (f32x4)0.f;

    // prologue loads (k0 = 0)
    float4 c0, c1, c2, c3;
    bf16x8 cb0, cb1;
    if (arow_ok) {
        c0 = *(const float4*)&xrow[shalf * 16 + 0];
        c1 = *(const float4*)&xrow[shalf * 16 + 4];
        c2 = *(const float4*)&xrow[shalf * 16 + 8];
        c3 = *(const float4*)&xrow[shalf * 16 + 12];
    } else {
        c0 = c1 = c2 = c3 = make_float4(0.f, 0.f, 0.f, 0.f);
    }
    cb0 = *(const bf16x8*)&wrow[shalf * 16];
    cb1 = *(const bf16x8*)&wrow[shalf * 16 + 8];

#pragma unroll
    for (int k0 = 0; k0 < IN_F; k0 += 32) {
        // ---- stage current into LDS ----
        {
            bf16x8 p0, p1;
            p0[0] = (short)f2bf(c0.x); p0[1] = (short)f2bf(c0.y);
            p0[2] = (short)f2bf(c0.z); p0[3] = (short)f2bf(c0.w);
            p0[4] = (short)f2bf(c1.x); p0[5] = (short)f2bf(c1.y);
            p0[6] = (short)f2bf(c1.z); p0[7] = (short)f2bf(c1.w);
            p1[0] = (short)f2bf(c2.x); p1[1] = (short)f2bf(c2.y);
            p1[2] = (short)f2bf(c2.z); p1[3] = (short)f2bf(c2.w);
            p1[4] = (short)f2bf(c3.x); p1[5] = (short)f2bf(c3.y);
            p1[6] = (short)f2bf(c3.z); p1[7] = (short)f2bf(c3.w);
            *(bf16x8*)&Albs[shalf * 2][srow][0]     = p0;
            *(bf16x8*)&Albs[shalf * 2 + 1][srow][0] = p1;
            *(bf16x8*)&Blbs[shalf * 2][srow][0]     = cb0;
            *(bf16x8*)&Blbs[shalf * 2 + 1][srow][0] = cb1;
        }
        // ---- prefetch next k-step (overlaps barrier + MFMA) ----
        float4 n0, n1, n2, n3;
        bf16x8 nb0, nb1;
        if (k0 + 32 < IN_F) {
            int kn = k0 + 32;
            if (arow_ok) {
                n0 = *(const float4*)&xrow[kn + shalf * 16 + 0];
                n1 = *(const float4*)&xrow[kn + shalf * 16 + 4];
                n2 = *(const float4*)&xrow[kn + shalf * 16 + 8];
                n3 = *(const float4*)&xrow[kn + shalf * 16 + 12];
            } else {
                n0 = n1 = n2 = n3 = make_float4(0.f, 0.f, 0.f, 0.f);
            }
            nb0 = *(const bf16x8*)&wrow[kn + shalf * 16];
            nb1 = *(const bf16x8*)&wrow[kn + shalf * 16 + 8];
        }
        __syncthreads();

        // ---- compute ----
        bf16x8 af[4], bfr[4];
#pragma unroll
        for (int m = 0; m < 4; ++m)
            af[m] = *(const bf16x8*)&Albs[kb][wr * 64 + m * 16 + fr][0];
#pragma unroll
        for (int n = 0; n < 4; ++n)
            bfr[n] = *(const bf16x8*)&Blbs[kb][wc * 64 + n * 16 + fr][0];
#pragma unroll
        for (int m = 0; m < 4; ++m)
#pragma unroll
            for (int n = 0; n < 4; ++n)
                acc[m][n] = __builtin_amdgcn_mfma_f32_16x16x32_bf16(af[m], bfr[n],
                                                                    acc[m][n], 0, 0, 0);
        __syncthreads();

        c0 = n0; c1 = n1; c2 = n2; c3 = n3;
        cb0 = nb0; cb1 = nb1;
    }

    // epilogue: C/D layout col=lane&15, row=(lane>>4)*4+reg ; write bf16
    const int crow0 = (lane >> 4) * 4;
    const int ccol = lane & 15;
#pragma unroll
    for (int m = 0; m < 4; ++m) {
#pragma unroll
        for (int reg = 0; reg < 4; ++reg) {
            int grow = block_row + wr * 64 + m * 16 + crow0 + reg;
            if (grow < N_NODES) {
#pragma unroll
                for (int n = 0; n < 4; ++n) {
                    int gcol = wc * 64 + n * 16 + ccol;
                    support_bf[(long)grow * OUT_F + gcol] = f2bf(acc[m][n][reg]);
                }
            }
        }
    }
}

// ---------------------------------------------------------------------------
// Bucket histogram (LDS-aggregated)
// ---------------------------------------------------------------------------
__global__ __launch_bounds__(1024) void bhist_kernel(const int* __restrict__ erow,
                                                     int* __restrict__ bucket_hist) {
    __shared__ int lh[NB];
    for (int i = threadIdx.x; i < NB; i += 1024) lh[i] = 0;
    __syncthreads();
    int e0 = blockIdx.x * TILE;
    int e1 = min(e0 + TILE, N_EDGES);
    for (int e = e0 + threadIdx.x; e < e1; e += 1024)
        atomicAdd(&lh[erow[e] / RPB], 1);
    __syncthreads();
    for (int i = threadIdx.x; i < NB; i += 1024)
        if (lh[i]) atomicAdd(&bucket_hist[i], lh[i]);
}

// ---------------------------------------------------------------------------
// Bucket scan (single block of 512)
// ---------------------------------------------------------------------------
__global__ __launch_bounds__(512) void bscan_kernel(const int* __restrict__ bucket_hist,
                                                    int* __restrict__ bucket_base,
                                                    int* __restrict__ bucket_cursor,
                                                    int* __restrict__ offsets) {
    __shared__ int p[512];
    const int tid = threadIdx.x;
    int v = bucket_hist[tid];
    p[tid] = v;
    __syncthreads();
#pragma unroll
    for (int off = 1; off < 512; off <<= 1) {
        int t = (tid >= off) ? p[tid - off] : 0;
        __syncthreads();
        p[tid] += t;
        __syncthreads();
    }
    bucket_base[tid] = p[tid] - v;
    bucket_cursor[tid] = p[tid] - v;
    if (tid == 511) bucket_base[512] = p[511];
    if (tid == 0) offsets[N_NODES] = N_EDGES;
}

// ---------------------------------------------------------------------------
// Pass 1: shuffle edges into bucket segments
// record = [val:f32 (63:32) | localrow:8 (31:24) | col:24 (23:0)]
// ---------------------------------------------------------------------------
__global__ __launch_bounds__(1024) void shuffle_kernel(const int* __restrict__ erow,
                                                       const int* __restrict__ ecol,
                                                       const float* __restrict__ eval,
                                                       int* __restrict__ bucket_cursor,
                                                       ull* __restrict__ bucketed) {
    __shared__ int lhist[NB];
    __shared__ int lbase[NB];
    const int e0 = blockIdx.x * TILE;
    const int e1 = min(e0 + TILE, N_EDGES);

    for (int i = threadIdx.x; i < NB; i += 1024) lhist[i] = 0;
    __syncthreads();
    for (int e = e0 + threadIdx.x; e < e1; e += 1024)
        atomicAdd(&lhist[erow[e] / RPB], 1);
    __syncthreads();
    for (int i = threadIdx.x; i < NB; i += 1024) {
        int c = lhist[i];
        lbase[i] = c ? atomicAdd(&bucket_cursor[i], c) : 0;
        lhist[i] = 0;                      // reuse as local cursor
    }
    __syncthreads();
    for (int e = e0 + threadIdx.x; e < e1; e += 1024) {
        int row = erow[e];                 // L2-hot re-read
        int b = row / RPB;
        int lr = row - b * RPB;
        int pos = lbase[b] + atomicAdd(&lhist[b], 1);
        ull rec = ((ull)__float_as_uint(eval[e]) << 32) |
                  ((unsigned)lr << 24) | (unsigned)ecol[e];
        bucketed[pos] = rec;
    }
}

// ---------------------------------------------------------------------------
// Pass 2: per-bucket counting sort by local row; emits offsets + sorted recs.
// ---------------------------------------------------------------------------
__global__ __launch_bounds__(256) void bsort_kernel(const int* __restrict__ bucket_base,
                                                    const ull* __restrict__ bucketed,
                                                    ull* __restrict__ sorted,
                                                    int* __restrict__ offsets) {
    const int b = blockIdx.x;
    const int r0 = b * RPB;
    if (r0 >= N_NODES) return;
    const int nrows = min(RPB, N_NODES - r0);
    const int start = bucket_base[b];
    const int cnt = bucket_base[b + 1] - start;

    __shared__ int lhist[RPB];
    __shared__ int lcur[RPB];
    __shared__ int lscan[256];
    const int tid = threadIdx.x;

    if (tid < RPB) lhist[tid] = 0;
    __syncthreads();
    for (int i = start + tid; i < start + cnt; i += 256) {
        int lr = (int)((bucketed[i] >> 24) & 0xFF);
        atomicAdd(&lhist[lr], 1);
    }
    __syncthreads();
    int v = (tid < RPB) ? lhist[tid] : 0;
    lscan[tid] = v;
    __syncthreads();
#pragma unroll
    for (int off = 1; off < 256; off <<= 1) {
        int t = (tid >= off) ? lscan[tid - off] : 0;
        __syncthreads();
        lscan[tid] += t;
        __syncthreads();
    }
    int excl = lscan[tid] - v;
    if (tid < nrows) {
        offsets[r0 + tid] = start + excl;
        lcur[tid] = excl;
    }
    __syncthreads();
    for (int i = start + tid; i < start + cnt; i += 256) {
        ull rec = bucketed[i];             // L2-hot second read
        int lr = (int)((rec >> 24) & 0xFF);
        int p = atomicAdd(&lcur[lr], 1);
        sorted[start + p] = rec;
    }
}

// ---------------------------------------------------------------------------
// SpMM: TWO rows per wave (independent gather chains for MLP); plain loads
// on sorted (L2-cached stream); NT store on out (write-once full lines).
// ---------------------------------------------------------------------------
__global__ __launch_bounds__(256) void spmm_kernel(const int* __restrict__ offsets,
                                                   const ull* __restrict__ sorted,
                                                   const unsigned short* __restrict__ sbf,
                                                   const float* __restrict__ b,
                                                   float* __restrict__ out) {
    const int wave = blockIdx.x * 4 + (threadIdx.x >> 6);
    const int lane = threadIdx.x & 63;
    const int r0 = wave * 2;
    if (r0 >= N_NODES) return;
    const bool has1 = (r0 + 1) < N_NODES;

    const int lo = lane * 2;
    const float2 bb = *(const float2*)&b[lo];

    const int sA = offsets[r0];
    const int eA = offsets[r0 + 1];
    const int sB = has1 ? eA : 0;
    const int eB = has1 ? offsets[r0 + 2] : 0;

    float2 accA = bb, accB = bb;

    int a = sA, c = sB;
    // fused main loop: 2 edges from each row -> 4 independent gathers in flight
    while (a + 2 <= eA && c + 2 <= eB) {
        ull ra0 = sorted[a];
        ull ra1 = sorted[a + 1];
        ull rc0 = sorted[c];
        ull rc1 = sorted[c + 1];
        unsigned ua0 = *(const unsigned*)&sbf[(long)(ra0 & 0xFFFFFF) * OUT_F + lo];
        unsigned ua1 = *(const unsigned*)&sbf[(long)(ra1 & 0xFFFFFF) * OUT_F + lo];
        unsigned uc0 = *(const unsigned*)&sbf[(long)(rc0 & 0xFFFFFF) * OUT_F + lo];
        unsigned uc1 = *(const unsigned*)&sbf[(long)(rc1 & 0xFFFFFF) * OUT_F + lo];
        float va0 = __uint_as_float((unsigned)(ra0 >> 32));
        float va1 = __uint_as_float((unsigned)(ra1 >> 32));
        float vc0 = __uint_as_float((unsigned)(rc0 >> 32));
        float vc1 = __uint_as_float((unsigned)(rc1 >> 32));
        accA.x += va0 * bflo(ua0) + va1 * bflo(ua1);
        accA.y += va0 * bfhi(ua0) + va1 * bfhi(ua1);
        accB.x += vc0 * bflo(uc0) + vc1 * bflo(uc1);
        accB.y += vc0 * bfhi(uc0) + vc1 * bfhi(uc1);
        a += 2; c += 2;
    }
    // drain row A (unroll-4 then scalar)
    for (; a + 4 <= eA; a += 4) {
        ull r0_ = sorted[a];
        ull r1_ = sorted[a + 1];
        ull r2_ = sorted[a + 2];
        ull r3_ = sorted[a + 3];
        unsigned u0 = *(const unsigned*)&sbf[(long)(r0_ & 0xFFFFFF) * OUT_F + lo];
        unsigned u1 = *(const unsigned*)&sbf[(long)(r1_ & 0xFFFFFF) * OUT_F + lo];
        unsigned u2 = *(const unsigned*)&sbf[(long)(r2_ & 0xFFFFFF) * OUT_F + lo];
        unsigned u3 = *(const unsigned*)&sbf[(long)(r3_ & 0xFFFFFF) * OUT_F + lo];
        float v0 = __uint_as_float((unsigned)(r0_ >> 32));
        float v1 = __uint_as_float((unsigned)(r1_ >> 32));
        float v2 = __uint_as_float((unsigned)(r2_ >> 32));
        float v3 = __uint_as_float((unsigned)(r3_ >> 32));
        accA.x += v0 * bflo(u0) + v1 * bflo(u1) + v2 * bflo(u2) + v3 * bflo(u3);
        accA.y += v0 * bfhi(u0) + v1 * bfhi(u1) + v2 * bfhi(u2) + v3 * bfhi(u3);
    }
    for (; a < eA; ++a) {
        ull r = sorted[a];
        unsigned u = *(const unsigned*)&sbf[(long)(r & 0xFFFFFF) * OUT_F + lo];
        float v = __uint_as_float((unsigned)(r >> 32));
        accA.x += v * bflo(u);
        accA.y += v * bfhi(u);
    }
    // drain row B
    for (; c + 4 <= eB; c += 4) {
        ull r0_ = sorted[c];
        ull r1_ = sorted[c + 1];
        ull r2_ = sorted[c + 2];
        ull r3_ = sorted[c + 3];
        unsigned u0 = *(const unsigned*)&sbf[(long)(r0_ & 0xFFFFFF) * OUT_F + lo];
        unsigned u1 = *(const unsigned*)&sbf[(long)(r1_ & 0xFFFFFF) * OUT_F + lo];
        unsigned u2 = *(const unsigned*)&sbf[(long)(r2_ & 0xFFFFFF) * OUT_F + lo];
        unsigned u3 = *(const unsigned*)&sbf[(long)(r3_ & 0xFFFFFF) * OUT_F + lo];
        float v0 = __uint_as_float((unsigned)(r0_ >> 32));
        float v1 = __uint_as_float((unsigned)(r1_ >> 32));
        float v2 = __uint_as_float((unsigned)(r2_ >> 32));
        float v3 = __uint_as_float((unsigned)(r3_ >> 32));
        accB.x += v0 * bflo(u0) + v1 * bflo(u1) + v2 * bflo(u2) + v3 * bflo(u3);
        accB.y += v0 * bfhi(u0) + v1 * bfhi(u1) + v2 * bfhi(u2) + v3 * bfhi(u3);
    }
    for (; c < eB; ++c) {
        ull r = sorted[c];
        unsigned u = *(const unsigned*)&sbf[(long)(r & 0xFFFFFF) * OUT_F + lo];
        float v = __uint_as_float((unsigned)(r >> 32));
        accB.x += v * bflo(u);
        accB.y += v * bfhi(u);
    }

    __builtin_nontemporal_store(*(double*)&accA, (double*)&out[(long)r0 * OUT_F + lo]);
    if (has1)
        __builtin_nontemporal_store(*(double*)&accB, (double*)&out[(long)(r0 + 1) * OUT_F + lo]);
}

extern "C" void kernel_launch(void* const* d_in, const int* in_sizes, int n_in,
                              void* d_out, int out_size, void* d_ws, size_t ws_size,
                              hipStream_t stream) {
    const float* x        = (const float*)d_in[0];
    const int*   edge_row = (const int*)d_in[1];
    const int*   edge_col = (const int*)d_in[2];
    const float* edge_val = (const float*)d_in[3];
    const float* weight   = (const float*)d_in[4];
    const float* bias     = (const float*)d_in[5];
    float* out = (float*)d_out;

    // workspace layout
    unsigned short* support_bf = (unsigned short*)d_ws;        // 12,800,000 u16 = 25.6 MB
    int* base_i        = (int*)d_ws + 6400000;
    int* bucket_hist   = base_i;                               // 512
    int* bucket_base   = base_i + 512;                         // 513
    int* bucket_cursor = base_i + 1032;                        // 512
    int* offsets       = base_i + 1544;                        // 100,001
    ull* bucketed = (ull*)(base_i + 101546);                   // 1,600,000 u64
    ull* sorted   = bucketed + N_EDGES;                        // 1,600,000 u64
    unsigned short* wt = (unsigned short*)(sorted + N_EDGES);  // 32,768 u16
    // total ≈ 52 MB

    // 0) W -> transposed bf16
    wconv_kernel<<<dim3(128), 256, 0, stream>>>(weight, wt);

    // 1) support_bf = bf16(X @ W)
    gemm_mfma_kernel<<<dim3((N_NODES + 127) / 128), 256, 0, stream>>>(x, wt, support_bf);

    // 2) bucket histogram
    hipMemsetAsync(bucket_hist, 0, NB * sizeof(int), stream);
    bhist_kernel<<<dim3(NTILES), 1024, 0, stream>>>(edge_row, bucket_hist);

    // 3) bucket scan -> base/cursor; offsets[N] = E
    bscan_kernel<<<dim3(1), 512, 0, stream>>>(bucket_hist, bucket_base, bucket_cursor, offsets);

    // 4) pass 1: shuffle into bucket segments
    shuffle_kernel<<<dim3(NTILES), 1024, 0, stream>>>(edge_row, edge_col, edge_val,
                                                      bucket_cursor, bucketed);

    // 5) pass 2: per-bucket counting sort -> sorted + offsets
    bsort_kernel<<<dim3(NBUSED), 256, 0, stream>>>(bucket_base, bucketed, sorted, offsets);

    // 6) SpMM: two rows per wave
    spmm_kernel<<<dim3((N_NODES / 2 + 3) / 4), 256, 0, stream>>>(offsets, sorted, support_bf,
                                                                 bias, out);
}